// Round 4
// baseline (214.583 us; speedup 1.0000x reference)
//
#include <hip/hip_runtime.h>
#include <cstdint>
#include <cstddef>

#define B 4
#define N 16
#define V 32
#define HW 25600
#define TOPK 7
#define CA 256
#define NCA (HW / CA)   // 100
#define CC 128
#define NCC (HW / CC)   // 200

__device__ __forceinline__ bool better(float av, int ai, float bv, int bi) {
    return (av > bv) || (av == bv && ai < bi);
}

// ---------------- kA: ms[n][v] + s2[n] partials per (b, 256px chunk) ----------------
// thread = (ng 8 x vo 4 x ps 8): 2n x 8v register tile (16 acc), feat from global.
__global__ __launch_bounds__(256) void kA(
    const float* __restrict__ feat, const float* __restrict__ gt,
    float* __restrict__ ms_part, float* __restrict__ s2_part) {
    int s = blockIdx.x;                  // 400
    int xcd = s & 7;
    int b = xcd >> 1;                    // pin each b to an XCD pair (L2 locality)
    int ch = (s >> 3) * 2 + (xcd & 1);   // 0..99
    int c0 = ch * CA;
    int tid = threadIdx.x;
    int ng = tid >> 5;                   // n pair {2ng, 2ng+1}
    int vo = (tid >> 3) & 3;             // v-octet
    int ps = tid & 7;                    // pixel slice

    __shared__ float g_lds[N][CA + 4];

    const float* fb = feat + ((size_t)b * V + vo * 8) * HW + c0;
    const float* gb = gt + (size_t)b * N * HW + c0;

    {   // stage gt tile: row tid>>4, 16 floats starting at (tid&15)*16
        int r = tid >> 4, c = (tid & 15) * 16;
        const float* src = gb + (size_t)r * HW + c;
        float4 a0 = *reinterpret_cast<const float4*>(src);
        float4 a1 = *reinterpret_cast<const float4*>(src + 4);
        float4 a2 = *reinterpret_cast<const float4*>(src + 8);
        float4 a3 = *reinterpret_cast<const float4*>(src + 12);
        *reinterpret_cast<float4*>(&g_lds[r][c]) = a0;
        *reinterpret_cast<float4*>(&g_lds[r][c + 4]) = a1;
        *reinterpret_cast<float4*>(&g_lds[r][c + 8]) = a2;
        *reinterpret_cast<float4*>(&g_lds[r][c + 12]) = a3;
    }
    __syncthreads();

    float acc[2][8];
#pragma unroll
    for (int i = 0; i < 2; ++i)
#pragma unroll
        for (int j = 0; j < 8; ++j) acc[i][j] = 0.f;
    float s2a0 = 0.f, s2a1 = 0.f;

    for (int it = 0; it < 8; ++it) {
        int p = it * 32 + ps * 4;
        float4 g0 = *reinterpret_cast<const float4*>(&g_lds[2 * ng][p]);
        float4 g1 = *reinterpret_cast<const float4*>(&g_lds[2 * ng + 1][p]);
        float ffx = 0.f, ffy = 0.f, ffz = 0.f, ffw = 0.f;
#pragma unroll
        for (int jh = 0; jh < 2; ++jh) {
            float4 f4[4];
#pragma unroll
            for (int j = 0; j < 4; ++j)
                f4[j] = *reinterpret_cast<const float4*>(fb + (size_t)(jh * 4 + j) * HW + p);
#pragma unroll
            for (int j = 0; j < 4; ++j) {
                int vi = jh * 4 + j;
                acc[0][vi] = fmaf(g0.x, f4[j].x, acc[0][vi]);
                acc[0][vi] = fmaf(g0.y, f4[j].y, acc[0][vi]);
                acc[0][vi] = fmaf(g0.z, f4[j].z, acc[0][vi]);
                acc[0][vi] = fmaf(g0.w, f4[j].w, acc[0][vi]);
                acc[1][vi] = fmaf(g1.x, f4[j].x, acc[1][vi]);
                acc[1][vi] = fmaf(g1.y, f4[j].y, acc[1][vi]);
                acc[1][vi] = fmaf(g1.z, f4[j].z, acc[1][vi]);
                acc[1][vi] = fmaf(g1.w, f4[j].w, acc[1][vi]);
                ffx = fmaf(f4[j].x, f4[j].x, ffx);
                ffy = fmaf(f4[j].y, f4[j].y, ffy);
                ffz = fmaf(f4[j].z, f4[j].z, ffz);
                ffw = fmaf(f4[j].w, f4[j].w, ffw);
            }
        }
        s2a0 = fmaf(g0.x, ffx, s2a0); s2a0 = fmaf(g0.y, ffy, s2a0);
        s2a0 = fmaf(g0.z, ffz, s2a0); s2a0 = fmaf(g0.w, ffw, s2a0);
        s2a1 = fmaf(g1.x, ffx, s2a1); s2a1 = fmaf(g1.y, ffy, s2a1);
        s2a1 = fmaf(g1.z, ffz, s2a1); s2a1 = fmaf(g1.w, ffw, s2a1);
    }

    // ms: reduce over ps (lane bits 0..2)
#pragma unroll
    for (int m = 1; m <= 4; m <<= 1)
#pragma unroll
        for (int i = 0; i < 2; ++i)
#pragma unroll
            for (int j = 0; j < 8; ++j) acc[i][j] += __shfl_xor(acc[i][j], m);
    size_t blk = (size_t)(b * NCA + ch);
    if (ps == 0) {
#pragma unroll
        for (int i = 0; i < 2; ++i)
#pragma unroll
            for (int j = 0; j < 8; ++j)
                ms_part[blk * 512 + (2 * ng + i) * 32 + vo * 8 + j] = acc[i][j];
    }
    // s2: reduce over (vo, ps) = lane bits 0..4
#pragma unroll
    for (int m = 1; m <= 16; m <<= 1) {
        s2a0 += __shfl_xor(s2a0, m);
        s2a1 += __shfl_xor(s2a1, m);
    }
    if ((tid & 31) == 0) {
        s2_part[blk * 16 + 2 * ng] = s2a0;
        s2_part[blk * 16 + 2 * ng + 1] = s2a1;
    }
}

// ---------------- kTop: per-(b,n) cnt + exact global top-7 + E-row gather ----------------
__global__ __launch_bounds__(256) void kTop(
    const float* __restrict__ pred, const float* __restrict__ gt,
    const float* __restrict__ feat,
    float* __restrict__ cntbuf, float* __restrict__ Ebuf) {
    int bn = blockIdx.x;
    int b = bn >> 4;
    int tid = threadIdx.x;
    int lane = tid & 63, wave = tid >> 6;
    const float* gtrow = gt + (size_t)bn * HW;
    const float* pr = pred + (size_t)b * HW;

    __shared__ float cv[TOPK * 256];
    __shared__ int   ci[TOPK * 256];
    __shared__ float rwv[4];
    __shared__ int   rwi[4], rws[4];
    __shared__ int   idx7[TOPK];
    __shared__ float csum[4];

    float tv[TOPK]; int ti[TOPK];
#pragma unroll
    for (int j = 0; j < TOPK; ++j) { tv[j] = -INFINITY; ti[j] = 0x7fffffff; }
    float cnt = 0.f;

    for (int k = 0; k < 25; ++k) {
        int p = k * 1024 + tid * 4;
        float4 g4 = *reinterpret_cast<const float4*>(gtrow + p);
        float4 p4 = *reinterpret_cast<const float4*>(pr + p);
        cnt += g4.x + g4.y + g4.z + g4.w;
        float ca[4] = { p4.x * g4.x, p4.y * g4.y, p4.z * g4.z, p4.w * g4.w };
#pragma unroll
        for (int j = 0; j < 4; ++j) {
            float c = ca[j]; int pi = p + j;
            if (better(c, pi, tv[TOPK - 1], ti[TOPK - 1])) {
                tv[TOPK - 1] = c; ti[TOPK - 1] = pi;
#pragma unroll
                for (int q = TOPK - 2; q >= 0; --q) {
                    if (better(tv[q + 1], ti[q + 1], tv[q], ti[q])) {
                        float fv = tv[q]; int fi = ti[q];
                        tv[q] = tv[q + 1]; ti[q] = ti[q + 1];
                        tv[q + 1] = fv; ti[q + 1] = fi;
                    }
                }
            }
        }
    }
#pragma unroll
    for (int off = 32; off > 0; off >>= 1) cnt += __shfl_down(cnt, off);
    if (lane == 0) csum[wave] = cnt;
#pragma unroll
    for (int j = 0; j < TOPK; ++j) { cv[j * 256 + tid] = tv[j]; ci[j * 256 + tid] = ti[j]; }
    __syncthreads();
    if (tid == 0) cntbuf[bn] = csum[0] + csum[1] + csum[2] + csum[3];

    for (int round = 0; round < TOPK; ++round) {
        float bv = -INFINITY; int bi = 0x7fffffff; int bs = -1;
#pragma unroll
        for (int j = 0; j < TOPK; ++j) {
            int slot = j * 256 + tid;
            float vv = cv[slot]; int ix = ci[slot];
            if (better(vv, ix, bv, bi)) { bv = vv; bi = ix; bs = slot; }
        }
#pragma unroll
        for (int off = 32; off > 0; off >>= 1) {
            float v2 = __shfl_down(bv, off);
            int i2 = __shfl_down(bi, off);
            int s2_ = __shfl_down(bs, off);
            if (better(v2, i2, bv, bi)) { bv = v2; bi = i2; bs = s2_; }
        }
        if (lane == 0) { rwv[wave] = bv; rwi[wave] = bi; rws[wave] = bs; }
        __syncthreads();
        if (tid == 0) {
            float fv = rwv[0]; int fi = rwi[0], fs = rws[0];
            for (int w = 1; w < 4; ++w)
                if (better(rwv[w], rwi[w], fv, fi)) { fv = rwv[w]; fi = rwi[w]; fs = rws[w]; }
            idx7[round] = fi;
            cv[fs] = -INFINITY; ci[fs] = 0x7fffffff;
        }
        __syncthreads();
    }

    if (tid < 224) {
        int r = tid >> 5, v = tid & 31;
        Ebuf[(size_t)bn * 256 + (r + 1) * 32 + v] =
            feat[((size_t)b * V + v) * HW + idx7[r]];
    }
}

// ---------------- kB: finalize mu + embedding-l2 ----------------
__global__ __launch_bounds__(64) void kB(
    const int* __restrict__ valid,
    const float* __restrict__ ms_part, const float* __restrict__ s2_part,
    const float* __restrict__ cntbuf,
    float* __restrict__ Ebuf, float* __restrict__ out) {
    int bn = blockIdx.x;
    int b = bn >> 4, n = bn & 15;
    int lane = threadIdx.x;

    float num = 0.f;
    if (lane < V) {
        const float* src = ms_part + (size_t)b * NCA * 512 + n * 32 + lane;
#pragma unroll 4
        for (int ch = 0; ch < NCA; ++ch) num += src[(size_t)ch * 512];
    }
    float s2v = 0.f;
    if (lane >= 32 && lane < 48) {
        int ss = lane & 15;
        const float* src = s2_part + (size_t)b * NCA * 16 + n;
        for (int ch = ss; ch < NCA; ch += 16) s2v += src[(size_t)ch * 16];
    }
#pragma unroll
    for (int m = 1; m <= 8; m <<= 1) s2v += __shfl_xor(s2v, m);
    float cnt = cntbuf[bn];
    float pix = fmaxf(cnt, 1.0f);
    float s2 = __shfl(s2v, 32);
    float mu = (lane < V) ? num / pix : 0.f;
    float msq = mu * mu;
#pragma unroll
    for (int m = 1; m <= 32; m <<= 1) msq += __shfl_xor(msq, m);
    if (lane == 0) atomicAdd(out + 2, (s2 / pix - msq) * (float)valid[bn]);
    if (lane < V) Ebuf[(size_t)bn * 256 + lane] = mu;
}

// ---------------- kC: sigmoid-GEMM dice partials (all 16 n per block) ----------------
// thread = (n 16 x pg 16): 8 rows x 4 px register tile (32 acc), feat/gt from global.
__global__ __launch_bounds__(256) void kC(
    const float* __restrict__ feat, const float* __restrict__ gt,
    const float* __restrict__ Ebuf, float* __restrict__ sums) {
    int s = blockIdx.x;                  // 800
    int xcd = s & 7;
    int b = xcd >> 1;
    int ch = (s >> 3) * 2 + (xcd & 1);   // 0..199
    int c0 = ch * CC;
    int tid = threadIdx.x;
    int n = tid >> 4, pg = tid & 15;

    __shared__ float e_lds[8 * 16 * 36];   // [r][n][36]: n-stride 36 -> conflict-free

    const float* eb = Ebuf + (size_t)b * 4096;
#pragma unroll
    for (int k = 0; k < 16; ++k) {
        int q = tid + 256 * k;
        int nn = q >> 8, rr = (q >> 5) & 7, vv = q & 31;
        e_lds[(rr * 16 + nn) * 36 + vv] = eb[q];
    }
    __syncthreads();

    const float* fb = feat + (size_t)b * V * HW + c0;
    const float* gn = gt + (size_t)(b * N + n) * HW + c0;

    float p2[8], tp[8];
#pragma unroll
    for (int r = 0; r < 8; ++r) { p2[r] = 0.f; tp[r] = 0.f; }

#pragma unroll
    for (int pass = 0; pass < 2; ++pass) {
        int p = pass * 64 + pg * 4;
        float acc[8][4];
#pragma unroll
        for (int r = 0; r < 8; ++r)
#pragma unroll
            for (int j = 0; j < 4; ++j) acc[r][j] = 0.f;

        for (int vq = 0; vq < 8; ++vq) {
            float4 f4[4];
#pragma unroll
            for (int j = 0; j < 4; ++j)
                f4[j] = *reinterpret_cast<const float4*>(fb + (size_t)(vq * 4 + j) * HW + p);
#pragma unroll
            for (int r = 0; r < 8; ++r) {
                float4 e4 = *reinterpret_cast<const float4*>(&e_lds[(r * 16 + n) * 36 + vq * 4]);
                acc[r][0] = fmaf(e4.x, f4[0].x, acc[r][0]);
                acc[r][0] = fmaf(e4.y, f4[1].x, acc[r][0]);
                acc[r][0] = fmaf(e4.z, f4[2].x, acc[r][0]);
                acc[r][0] = fmaf(e4.w, f4[3].x, acc[r][0]);
                acc[r][1] = fmaf(e4.x, f4[0].y, acc[r][1]);
                acc[r][1] = fmaf(e4.y, f4[1].y, acc[r][1]);
                acc[r][1] = fmaf(e4.z, f4[2].y, acc[r][1]);
                acc[r][1] = fmaf(e4.w, f4[3].y, acc[r][1]);
                acc[r][2] = fmaf(e4.x, f4[0].z, acc[r][2]);
                acc[r][2] = fmaf(e4.y, f4[1].z, acc[r][2]);
                acc[r][2] = fmaf(e4.z, f4[2].z, acc[r][2]);
                acc[r][2] = fmaf(e4.w, f4[3].z, acc[r][2]);
                acc[r][3] = fmaf(e4.x, f4[0].w, acc[r][3]);
                acc[r][3] = fmaf(e4.y, f4[1].w, acc[r][3]);
                acc[r][3] = fmaf(e4.z, f4[2].w, acc[r][3]);
                acc[r][3] = fmaf(e4.w, f4[3].w, acc[r][3]);
            }
        }

        float4 g4 = *reinterpret_cast<const float4*>(gn + p);
        float ga[4] = { g4.x, g4.y, g4.z, g4.w };
#pragma unroll
        for (int r = 0; r < 8; ++r)
#pragma unroll
            for (int j = 0; j < 4; ++j) {
                float sg = 1.f / (1.f + __expf(-acc[r][j]));
                p2[r] = fmaf(sg, sg, p2[r]);
                tp[r] = fmaf(ga[j], sg, tp[r]);
            }
    }

    // reduce over pg (lane bits 0..3)
#pragma unroll
    for (int m = 1; m <= 8; m <<= 1)
#pragma unroll
        for (int r = 0; r < 8; ++r) {
            p2[r] += __shfl_xor(p2[r], m);
            tp[r] += __shfl_xor(tp[r], m);
        }
    if (pg == 0) {
        int base = (b * 16 + n) * 16;
#pragma unroll
        for (int r = 0; r < 8; ++r) {
            atomicAdd(sums + base + r * 2, p2[r]);
            atomicAdd(sums + base + r * 2 + 1, tp[r]);
        }
    }
}

// ---------------- kD: fold dice sums into losses ----------------
__global__ void kD(const float* __restrict__ sums, const float* __restrict__ cntbuf,
                   const int* __restrict__ valid, float* __restrict__ out) {
    int bn = threadIdx.x;   // 64 threads
    float vw = (float)valid[bn];
    float cnt = cntbuf[bn];
    float mloss = 0.f, iloss = 0.f;
#pragma unroll
    for (int r = 0; r < 8; ++r) {
        float p2 = sums[bn * 16 + r * 2];
        float tp = sums[bn * 16 + r * 2 + 1];
        float denom = fmaxf(p2 + cnt, 1e-8f);
        float dice = 1.f - 2.f * tp / denom;
        if (r == 0) mloss = dice * vw;
        else iloss += dice * vw;
    }
    atomicAdd(out + 0, mloss);
    atomicAdd(out + 1, iloss);
}

extern "C" void kernel_launch(void* const* d_in, const int* in_sizes, int n_in,
                              void* d_out, int out_size, void* d_ws, size_t ws_size,
                              hipStream_t stream) {
    const float* pred = (const float*)d_in[0];
    const float* feat = (const float*)d_in[1];
    const float* gtin = (const float*)d_in[2];
    const int* valid  = (const int*)d_in[3];
    float* out = (float*)d_out;

    char* ws = (char*)d_ws;
    float* ms_part = (float*)(ws);            // 400*512*4 = 819200
    float* s2_part = (float*)(ws + 819200);   // 400*16*4  =  25600
    float* Ebuf    = (float*)(ws + 844800);   // 64*256*4  =  65536
    float* cntbuf  = (float*)(ws + 910336);   // 256
    float* sums    = (float*)(ws + 910592);   // 64*16*4   =   4096

    hipMemsetAsync(out, 0, 3 * sizeof(float), stream);
    hipMemsetAsync(sums, 0, 64 * 16 * sizeof(float), stream);

    kA<<<B * NCA, 256, 0, stream>>>(feat, gtin, ms_part, s2_part);
    kTop<<<B * N, 256, 0, stream>>>(pred, gtin, feat, cntbuf, Ebuf);
    kB<<<B * N, 64, 0, stream>>>(valid, ms_part, s2_part, cntbuf, Ebuf, out);
    kC<<<B * NCC, 256, 0, stream>>>(feat, gtin, Ebuf, sums);
    kD<<<1, 64, 0, stream>>>(sums, cntbuf, valid, out);
}